// Round 14
// baseline (196.750 us; speedup 1.0000x reference)
//
#include <hip/hip_runtime.h>
#include <hip/hip_bf16.h>
#include <stdint.h>

#define T_SEQ 4096
#define DIMX 1024
#define NH 16
#define HD 64
#define DLAT 256

typedef __bf16 bf16x8 __attribute__((ext_vector_type(8)));
typedef __bf16 bf16x4 __attribute__((ext_vector_type(4)));
typedef float floatx4 __attribute__((ext_vector_type(4)));

#define MFMA(a, b, c) __builtin_amdgcn_mfma_f32_16x16x32_bf16(a, b, c, 0, 0, 0)

__device__ inline void gload_lds16(const __bf16* g, __bf16* l) {
  __builtin_amdgcn_global_load_lds(
      (const __attribute__((address_space(1))) uint32_t*)g,
      (__attribute__((address_space(3))) uint32_t*)l, 16, 0, 0);
}

// ---------- prep: x f32->bf16 convert + 5 weight transposes -----------------
__global__ __launch_bounds__(256) void prep_kernel(
    const float* __restrict__ x, const float* __restrict__ wdkv,
    const float* __restrict__ wuk, const float* __restrict__ wuv,
    const float* __restrict__ wuq, const float* __restrict__ wo,
    __bf16* __restrict__ x_bf, __bf16* __restrict__ wt_dkv,
    __bf16* __restrict__ wt_uk, __bf16* __restrict__ wt_uv,
    __bf16* __restrict__ wt_uq, __bf16* __restrict__ wt_o) {
  int id = blockIdx.x;
  if (id < 2048) {
    int i = id * 256 + threadIdx.x;
    const float4* p = (const float4*)x;
    float4 a = p[2 * i], b = p[2 * i + 1];
    bf16x8 r = {(__bf16)a.x, (__bf16)a.y, (__bf16)a.z, (__bf16)a.w,
                (__bf16)b.x, (__bf16)b.y, (__bf16)b.z, (__bf16)b.w};
    *(bf16x8*)(x_bf + 8 * (size_t)i) = r;
    return;
  }
  int t = id - 2048;
  const float* in;
  __bf16* out;
  int R, C, lt;
  if (t < 64)       { in = wdkv; out = wt_dkv; R = 1024; C = 256;  lt = t; }
  else if (t < 128) { in = wuk;  out = wt_uk;  R = 256;  C = 1024; lt = t - 64; }
  else if (t < 192) { in = wuv;  out = wt_uv;  R = 256;  C = 1024; lt = t - 128; }
  else if (t < 448) { in = wuq;  out = wt_uq;  R = 1024; C = 1024; lt = t - 192; }
  else              { in = wo;   out = wt_o;   R = 1024; C = 1024; lt = t - 448; }
  __shared__ __bf16 tls[64][65];
  int tpr = C >> 6;
  int r0 = (lt / tpr) * 64, c0 = (lt % tpr) * 64;
  int tid = threadIdx.x;
#pragma unroll
  for (int i = 0; i < 16; i++) {
    int idx = tid + i * 256;
    int r = idx >> 6, c = idx & 63;
    tls[r][c] = (__bf16)in[(size_t)(r0 + r) * C + c0 + c];
  }
  __syncthreads();
#pragma unroll
  for (int i = 0; i < 2; i++) {
    int idx = tid + i * 256;      // 0..511
    int cc = idx >> 3;            // output row (source col) 0..63
    int rr8 = (idx & 7) * 8;      // 8-wide output col group
    bf16x8 v;
#pragma unroll
    for (int j = 0; j < 8; j++) v[j] = tls[rr8 + j][cc];
    *(bf16x8*)&out[(size_t)(c0 + cc) * R + r0 + rr8] = v;
  }
}

// ======== GEMM tiles (r9-validated 2-barrier structure; no SW pipelining —
// r12/r13 falsified intra-block dbuf for these shapes) =======================
#define BUFE 4096   // 128 rows x 32 cols (A tile per kh)
#define BUFEB 2048  // 64 rows x 32 cols (B tile per kh)

// ---------- gemm_a64: 128x64 tiles. ckv = x@Wdkv' (bx<4), q = s*x@Wuq' ------
// q scale folds 1/8 (softmax scale) * log2(e) so attn can use exp2.
__global__ __launch_bounds__(256) void gemm_a64(const __bf16* __restrict__ A,
                                                const __bf16* __restrict__ B1,
                                                const __bf16* __restrict__ B2,
                                                __bf16* __restrict__ C1,
                                                __bf16* __restrict__ C2) {
  __shared__ __attribute__((aligned(16))) __bf16 Al[2][BUFE];
  __shared__ __attribute__((aligned(16))) __bf16 Bl[2][BUFEB];
  int tid = threadIdx.x;
  int w = tid >> 6, lane = tid & 63;
  int quad = lane >> 4, l16 = lane & 15;
  int mw = w & 1, nw = w >> 1;
  int bx = blockIdx.x, m0 = blockIdx.y * 128;
  const __bf16* Bt;
  __bf16* C;
  int n0, N;
  float sc;
  if (bx < 4) { Bt = B1; C = C1; n0 = bx * 64; N = DLAT; sc = 1.0f; }
  else        { Bt = B2; C = C2; n0 = (bx - 4) * 64; N = DIMX;
                sc = 0.125f * 1.44269504088896340736f; }
  const int K = DIMX;
  int arow = w * 32 + (lane >> 2), acol = (lane & 3) << 3;
  int brow = w * 16 + (lane >> 2);

  floatx4 acc[4][2];
#pragma unroll
  for (int i = 0; i < 4; i++)
#pragma unroll
    for (int j = 0; j < 2; j++) acc[i][j] = (floatx4){0.f, 0.f, 0.f, 0.f};

  for (int k0 = 0; k0 < K; k0 += 64) {
#pragma unroll
    for (int kh = 0; kh < 2; kh++) {
#pragma unroll
      for (int j = 0; j < 2; j++)
        gload_lds16(A + (size_t)(m0 + arow + j * 16) * K + k0 + kh * 32 + acol,
                    &Al[kh][(w * 32 + j * 16) * 32]);
      gload_lds16(Bt + (size_t)(n0 + brow) * K + k0 + kh * 32 + acol,
                  &Bl[kh][(w * 16) * 32]);
    }
    __syncthreads();
#pragma unroll
    for (int kh = 0; kh < 2; kh++) {
      bf16x8 af[4], bfr[2];
#pragma unroll
      for (int mt = 0; mt < 4; mt++)
        af[mt] =
            *(const bf16x8*)&Al[kh][(mw * 64 + mt * 16 + l16) * 32 + quad * 8];
#pragma unroll
      for (int nt = 0; nt < 2; nt++)
        bfr[nt] =
            *(const bf16x8*)&Bl[kh][(nw * 32 + nt * 16 + l16) * 32 + quad * 8];
#pragma unroll
      for (int mt = 0; mt < 4; mt++)
#pragma unroll
        for (int nt = 0; nt < 2; nt++)
          acc[mt][nt] = MFMA(af[mt], bfr[nt], acc[mt][nt]);
    }
    __syncthreads();
  }
#pragma unroll
  for (int mt = 0; mt < 4; mt++)
#pragma unroll
    for (int nt = 0; nt < 2; nt++)
#pragma unroll
      for (int r = 0; r < 4; r++) {
        int row = m0 + mw * 64 + mt * 16 + quad * 4 + r;
        int col = n0 + nw * 32 + nt * 16 + l16;
        C[(size_t)row * N + col] = (__bf16)(acc[mt][nt][r] * sc);
      }
}

// ---------- gemm_kv64: 128x64 tiles. k = ckv@Wuk' (bx<16); vt (bx>=16) ------
// r14: gemm_kv was the last GEMM at 2 blocks/CU (512 blocks) and the most
// fill-dominated (K=256 -> 4 steps). 128x64 -> 1024 blocks, LDS 42KB ->
// 3 blocks/CU resident, mirroring the r9-validated residency fix.
__global__ __launch_bounds__(256) void gemm_kv64(const __bf16* __restrict__ A,
                                                 const __bf16* __restrict__ Bk,
                                                 const __bf16* __restrict__ Bv,
                                                 __bf16* __restrict__ k,
                                                 __bf16* __restrict__ vt) {
  __shared__ __attribute__((aligned(16))) __bf16 Al[2][BUFE];
  __shared__ __attribute__((aligned(16))) __bf16 Bl[2][BUFEB];
  __shared__ __attribute__((aligned(16))) __bf16 tw[4][32 * 72];
  int tid = threadIdx.x;
  int w = tid >> 6, lane = tid & 63;
  int quad = lane >> 4, l16 = lane & 15;
  int mw = w & 1, nw = w >> 1;
  int bx = blockIdx.x, m0 = blockIdx.y * 128;
  bool is_k = (bx < 16);
  const __bf16* Bt = is_k ? Bk : Bv;
  int n0 = (is_k ? bx : bx - 16) * 64;
  const int K = DLAT;
  int arow = w * 32 + (lane >> 2), acol = (lane & 3) << 3;
  int brow = w * 16 + (lane >> 2);

  floatx4 acc[4][2];
#pragma unroll
  for (int i = 0; i < 4; i++)
#pragma unroll
    for (int j = 0; j < 2; j++) acc[i][j] = (floatx4){0.f, 0.f, 0.f, 0.f};

  for (int k0 = 0; k0 < K; k0 += 64) {
#pragma unroll
    for (int kh = 0; kh < 2; kh++) {
#pragma unroll
      for (int j = 0; j < 2; j++)
        gload_lds16(A + (size_t)(m0 + arow + j * 16) * K + k0 + kh * 32 + acol,
                    &Al[kh][(w * 32 + j * 16) * 32]);
      gload_lds16(Bt + (size_t)(n0 + brow) * K + k0 + kh * 32 + acol,
                  &Bl[kh][(w * 16) * 32]);
    }
    __syncthreads();
#pragma unroll
    for (int kh = 0; kh < 2; kh++) {
      bf16x8 af[4], bfr[2];
#pragma unroll
      for (int mt = 0; mt < 4; mt++)
        af[mt] =
            *(const bf16x8*)&Al[kh][(mw * 64 + mt * 16 + l16) * 32 + quad * 8];
#pragma unroll
      for (int nt = 0; nt < 2; nt++)
        bfr[nt] =
            *(const bf16x8*)&Bl[kh][(nw * 32 + nt * 16 + l16) * 32 + quad * 8];
#pragma unroll
      for (int mt = 0; mt < 4; mt++)
#pragma unroll
        for (int nt = 0; nt < 2; nt++)
          acc[mt][nt] = MFMA(af[mt], bfr[nt], acc[mt][nt]);
    }
    __syncthreads();
  }
  if (is_k) {
#pragma unroll
    for (int mt = 0; mt < 4; mt++)
#pragma unroll
      for (int nt = 0; nt < 2; nt++)
#pragma unroll
        for (int r = 0; r < 4; r++) {
          int row = m0 + mw * 64 + mt * 16 + quad * 4 + r;
          int col = n0 + nw * 32 + nt * 16 + l16;
          k[(size_t)row * DIMX + col] = (__bf16)acc[mt][nt][r];
        }
  } else {
    // stage wave's 32col x 64row sub-tile as [col][row], then vectorized write
#pragma unroll
    for (int mt = 0; mt < 4; mt++)
#pragma unroll
      for (int nt = 0; nt < 2; nt++)
#pragma unroll
        for (int r = 0; r < 4; r++)
          tw[w][(nt * 16 + l16) * 72 + mt * 16 + quad * 4 + r] =
              (__bf16)acc[mt][nt][r];
    int c = lane & 31, half = lane >> 5;  // 2 lanes/col; halves of 8 chunks
#pragma unroll
    for (int i = 0; i < 4; i++) {
      int chunk = half * 4 + i;  // 8-row chunk index 0..7
      bf16x8 v8 = *(const bf16x8*)&tw[w][c * 72 + chunk * 8];
      *(bf16x8*)&vt[(size_t)(n0 + nw * 32 + c) * T_SEQ + m0 + mw * 64 +
                    chunk * 8] = v8;
    }
  }
}

// ---------- gemm_f64: out(f32) = ctx @ Wo', 128x64 tiles (512 blocks) ------
__global__ __launch_bounds__(256) void gemm_f64(const __bf16* __restrict__ A,
                                                const __bf16* __restrict__ Bt,
                                                float* __restrict__ C) {
  __shared__ __attribute__((aligned(16))) __bf16 Al[2][BUFE];
  __shared__ __attribute__((aligned(16))) __bf16 Bl[2][BUFEB];
  int tid = threadIdx.x;
  int w = tid >> 6, lane = tid & 63;
  int quad = lane >> 4, l16 = lane & 15;
  int mw = w & 1, nw = w >> 1;
  int n0 = blockIdx.x * 64, m0 = blockIdx.y * 128;
  const int K = DIMX, N = DIMX;
  int arow = w * 32 + (lane >> 2), acol = (lane & 3) << 3;
  int brow = w * 16 + (lane >> 2);

  floatx4 acc[4][2];
#pragma unroll
  for (int i = 0; i < 4; i++)
#pragma unroll
    for (int j = 0; j < 2; j++) acc[i][j] = (floatx4){0.f, 0.f, 0.f, 0.f};

  for (int k0 = 0; k0 < K; k0 += 64) {
#pragma unroll
    for (int kh = 0; kh < 2; kh++) {
#pragma unroll
      for (int j = 0; j < 2; j++)
        gload_lds16(A + (size_t)(m0 + arow + j * 16) * K + k0 + kh * 32 + acol,
                    &Al[kh][(w * 32 + j * 16) * 32]);
      gload_lds16(Bt + (size_t)(n0 + brow) * K + k0 + kh * 32 + acol,
                  &Bl[kh][(w * 16) * 32]);
    }
    __syncthreads();
#pragma unroll
    for (int kh = 0; kh < 2; kh++) {
      bf16x8 af[4], bfr[2];
#pragma unroll
      for (int mt = 0; mt < 4; mt++)
        af[mt] =
            *(const bf16x8*)&Al[kh][(mw * 64 + mt * 16 + l16) * 32 + quad * 8];
#pragma unroll
      for (int nt = 0; nt < 2; nt++)
        bfr[nt] =
            *(const bf16x8*)&Bl[kh][(nw * 32 + nt * 16 + l16) * 32 + quad * 8];
#pragma unroll
      for (int mt = 0; mt < 4; mt++)
#pragma unroll
        for (int nt = 0; nt < 2; nt++)
          acc[mt][nt] = MFMA(af[mt], bfr[nt], acc[mt][nt]);
    }
    __syncthreads();
  }
#pragma unroll
  for (int mt = 0; mt < 4; mt++)
#pragma unroll
    for (int nt = 0; nt < 2; nt++)
#pragma unroll
      for (int r = 0; r < 4; r++) {
        int row = m0 + mw * 64 + mt * 16 + quad * 4 + r;
        int col = n0 + nw * 32 + nt * 16 + l16;
        C[(size_t)row * N + col] = acc[mt][nt][r];
      }
}

// ---------- flash attention v12 (validated: 67.5-70.4us steady-state) -------
// DMA staging with pre-swizzled global source, linear LDS dest (rule #21).
#define PST 72
__global__ __launch_bounds__(256, 3) void mla_attn12(
    const __bf16* __restrict__ Q, const __bf16* __restrict__ Kg,
    const __bf16* __restrict__ Vt, __bf16* __restrict__ ctx) {
  __shared__ __attribute__((aligned(16))) __bf16 Kl[2][64 * 64];
  __shared__ __attribute__((aligned(16))) __bf16 Vl[2][64 * 64];
  __shared__ __attribute__((aligned(16))) __bf16 Pl[64 * PST];
  int tid = threadIdx.x;
  int wave = tid >> 6, lane = tid & 63;
  int quad = lane >> 4, l16 = lane & 15;
  int h = blockIdx.x;        // heads vary fastest in dispatch order
  int qt = 63 - blockIdx.y;  // global LPT: all large blocks dispatch first
  int q0 = qt * 64;
  int srow = tid >> 3, pos = tid & 7;  // srow 0..31, rows srow and srow+32
  int gco = pos << 3;
  int sw = (pos ^ (srow & 7)) << 3;    // pre-swizzled source column (elements)
  int fr = (wave * 16 + l16) * PST;
  int c0s = ((quad ^ (l16 & 7)) << 3);
  int c1s = (((4 + quad) ^ (l16 & 7)) << 3);
  int wb = wave * 512;  // wave-uniform LDS base (elements)

  *(bf16x8*)&Pl[srow * PST + gco] =
      *(const bf16x8*)&Q[(size_t)(q0 + srow) * DIMX + h * HD + gco];
  *(bf16x8*)&Pl[(srow + 32) * PST + gco] =
      *(const bf16x8*)&Q[(size_t)(q0 + srow + 32) * DIMX + h * HD + gco];
  gload_lds16(&Kg[(size_t)srow * DIMX + h * HD + sw], &Kl[0][wb]);
  gload_lds16(&Kg[(size_t)(srow + 32) * DIMX + h * HD + sw], &Kl[0][2048 + wb]);
  gload_lds16(&Vt[(size_t)(h * HD + srow) * T_SEQ + sw], &Vl[0][wb]);
  gload_lds16(&Vt[(size_t)(h * HD + srow + 32) * T_SEQ + sw], &Vl[0][2048 + wb]);
  __syncthreads();
  bf16x8 qf0 = *(const bf16x8*)&Pl[fr + quad * 8];
  bf16x8 qf1 = *(const bf16x8*)&Pl[fr + 32 + quad * 8];

  floatx4 o[4];
  float lsum = 0.f;
#pragma unroll
  for (int i = 0; i < 4; i++) o[i] = (floatx4){0.f, 0.f, 0.f, 0.f};

  for (int kt = 0; kt <= qt; kt++) {
    int cur = kt & 1, nxt = cur ^ 1;
    bool pre = (kt < qt);
    if (pre) {  // DMA next tile into nxt (quiesced by the previous barrier)
      int k0n = (kt + 1) * 64;
      gload_lds16(&Kg[(size_t)(k0n + srow) * DIMX + h * HD + sw],
                  &Kl[nxt][wb]);
      gload_lds16(&Kg[(size_t)(k0n + srow + 32) * DIMX + h * HD + sw],
                  &Kl[nxt][2048 + wb]);
      gload_lds16(&Vt[(size_t)(h * HD + srow) * T_SEQ + k0n + sw],
                  &Vl[nxt][wb]);
      gload_lds16(&Vt[(size_t)(h * HD + srow + 32) * T_SEQ + k0n + sw],
                  &Vl[nxt][2048 + wb]);
    }
    const __bf16* Kc = Kl[cur];
    const __bf16* Vc = Vl[cur];
    floatx4 s[4];
    __builtin_amdgcn_s_setprio(1);
#pragma unroll
    for (int ct = 0; ct < 4; ct++) {
      int rb = (ct * 16 + l16) * 64;
      bf16x8 kf0 = *(const bf16x8*)&Kc[rb + c0s];
      bf16x8 kf1 = *(const bf16x8*)&Kc[rb + c1s];
      floatx4 z = (floatx4){0.f, 0.f, 0.f, 0.f};
      z = MFMA(kf0, qf0, z);  // swapped: lane holds P[q=l16][k=ct*16+quad*4+r]
      z = MFMA(kf1, qf1, z);
      s[ct] = z;
    }
    __builtin_amdgcn_s_setprio(0);
    bool diag = (kt == qt);
#pragma unroll
    for (int ct = 0; ct < 4; ct++) {
      float p0[4];
#pragma unroll
      for (int r = 0; r < 4; r++) {
        float p = __builtin_amdgcn_exp2f(s[ct][r]);
        if (diag && (ct * 16 + quad * 4 + r > wave * 16 + l16)) p = 0.f;
        lsum += p;
        p0[r] = p;
      }
      bf16x4 pk = {(__bf16)p0[0], (__bf16)p0[1], (__bf16)p0[2], (__bf16)p0[3]};
      *(bf16x4*)&Pl[(wave * 16 + l16) * PST + ct * 16 + quad * 4] = pk;
    }
    bf16x8 pf0 = *(const bf16x8*)&Pl[fr + quad * 8];
    bf16x8 pf1 = *(const bf16x8*)&Pl[fr + 32 + quad * 8];
    __builtin_amdgcn_s_setprio(1);
#pragma unroll
    for (int dt = 0; dt < 4; dt++) {
      int rb = (dt * 16 + l16) * 64;
      bf16x8 vf0 = *(const bf16x8*)&Vc[rb + c0s];
      bf16x8 vf1 = *(const bf16x8*)&Vc[rb + c1s];
      o[dt] = MFMA(pf0, vf0, o[dt]);
      o[dt] = MFMA(pf1, vf1, o[dt]);
    }
    __builtin_amdgcn_s_setprio(0);
    __syncthreads();
  }

  lsum += __shfl_xor(lsum, 16, 64);
  lsum += __shfl_xor(lsum, 32, 64);
  float inv[4];
#pragma unroll
  for (int r = 0; r < 4; r++) inv[r] = 1.0f / __shfl(lsum, quad * 4 + r, 16);

#pragma unroll
  for (int dt = 0; dt < 4; dt++)
#pragma unroll
    for (int r = 0; r < 4; r++) {
      float val = o[dt][r] * inv[r];
      int row = q0 + wave * 16 + quad * 4 + r;
      int col = h * HD + dt * 16 + l16;
      ctx[(size_t)row * DIMX + col] = (__bf16)val;
    }
}

extern "C" void kernel_launch(void* const* d_in, const int* in_sizes, int n_in,
                              void* d_out, int out_size, void* d_ws,
                              size_t ws_size, hipStream_t stream) {
  const float* x = (const float*)d_in[0];
  const float* wdkv = (const float*)d_in[1];
  const float* wuk = (const float*)d_in[2];
  const float* wuv = (const float*)d_in[3];
  const float* wuq = (const float*)d_in[4];
  const float* wo = (const float*)d_in[5];
  float* out = (float*)d_out;

  __bf16* ws = (__bf16*)d_ws;
  __bf16* x_bf = ws;                               // T*D
  __bf16* q = x_bf + (size_t)T_SEQ * DIMX;         // T*D (pre-scaled)
  __bf16* k = q + (size_t)T_SEQ * DIMX;            // T*D
  __bf16* vt = k + (size_t)T_SEQ * DIMX;           // D*T
  __bf16* ctx = vt + (size_t)T_SEQ * DIMX;         // T*D
  __bf16* ckv = ctx + (size_t)T_SEQ * DIMX;        // T*DLAT
  __bf16* wt_dkv = ckv + (size_t)T_SEQ * DLAT;     // DLAT x DIM
  __bf16* wt_uk = wt_dkv + (size_t)DLAT * DIMX;    // DIM x DLAT
  __bf16* wt_uv = wt_uk + (size_t)DIMX * DLAT;     // DIM x DLAT
  __bf16* wt_uq = wt_uv + (size_t)DIMX * DLAT;     // DIM x DIM
  __bf16* wt_o = wt_uq + (size_t)DIMX * DIMX;      // DIM x DIM

  dim3 blk(256);
  prep_kernel<<<dim3(2752), blk, 0, stream>>>(x, wdkv, wuk, wuv, wuq, wo, x_bf,
                                              wt_dkv, wt_uk, wt_uv, wt_uq, wt_o);
  gemm_a64<<<dim3(20, T_SEQ / 128), blk, 0, stream>>>(x_bf, wt_dkv, wt_uq,
                                                      ckv, q);
  gemm_kv64<<<dim3(32, T_SEQ / 128), blk, 0, stream>>>(ckv, wt_uk, wt_uv, k,
                                                       vt);
  mla_attn12<<<dim3(NH, 64), dim3(256), 0, stream>>>(q, k, vt, ctx);
  gemm_f64<<<dim3(DIMX / 64, T_SEQ / 128), blk, 0, stream>>>(ctx, wt_o, out);
}

// Round 15
// 189.702 us; speedup vs baseline: 1.0372x; 1.0372x over previous
//
#include <hip/hip_runtime.h>
#include <hip/hip_bf16.h>
#include <stdint.h>

#define T_SEQ 4096
#define DIMX 1024
#define NH 16
#define HD 64
#define DLAT 256

typedef __bf16 bf16x8 __attribute__((ext_vector_type(8)));
typedef __bf16 bf16x4 __attribute__((ext_vector_type(4)));
typedef float floatx4 __attribute__((ext_vector_type(4)));

#define MFMA(a, b, c) __builtin_amdgcn_mfma_f32_16x16x32_bf16(a, b, c, 0, 0, 0)

__device__ inline void gload_lds16(const __bf16* g, __bf16* l) {
  __builtin_amdgcn_global_load_lds(
      (const __attribute__((address_space(1))) uint32_t*)g,
      (__attribute__((address_space(3))) uint32_t*)l, 16, 0, 0);
}

// ---------- prep: x f32->bf16 convert + 5 weight transposes -----------------
// v2 (r11-validated): transpose write phase vectorized to bf16x8.
__global__ __launch_bounds__(256) void prep_kernel(
    const float* __restrict__ x, const float* __restrict__ wdkv,
    const float* __restrict__ wuk, const float* __restrict__ wuv,
    const float* __restrict__ wuq, const float* __restrict__ wo,
    __bf16* __restrict__ x_bf, __bf16* __restrict__ wt_dkv,
    __bf16* __restrict__ wt_uk, __bf16* __restrict__ wt_uv,
    __bf16* __restrict__ wt_uq, __bf16* __restrict__ wt_o) {
  int id = blockIdx.x;
  if (id < 2048) {
    int i = id * 256 + threadIdx.x;
    const float4* p = (const float4*)x;
    float4 a = p[2 * i], b = p[2 * i + 1];
    bf16x8 r = {(__bf16)a.x, (__bf16)a.y, (__bf16)a.z, (__bf16)a.w,
                (__bf16)b.x, (__bf16)b.y, (__bf16)b.z, (__bf16)b.w};
    *(bf16x8*)(x_bf + 8 * (size_t)i) = r;
    return;
  }
  int t = id - 2048;
  const float* in;
  __bf16* out;
  int R, C, lt;
  if (t < 64)       { in = wdkv; out = wt_dkv; R = 1024; C = 256;  lt = t; }
  else if (t < 128) { in = wuk;  out = wt_uk;  R = 256;  C = 1024; lt = t - 64; }
  else if (t < 192) { in = wuv;  out = wt_uv;  R = 256;  C = 1024; lt = t - 128; }
  else if (t < 448) { in = wuq;  out = wt_uq;  R = 1024; C = 1024; lt = t - 192; }
  else              { in = wo;   out = wt_o;   R = 1024; C = 1024; lt = t - 448; }
  __shared__ __bf16 tls[64][65];
  int tpr = C >> 6;
  int r0 = (lt / tpr) * 64, c0 = (lt % tpr) * 64;
  int tid = threadIdx.x;
#pragma unroll
  for (int i = 0; i < 16; i++) {
    int idx = tid + i * 256;
    int r = idx >> 6, c = idx & 63;
    tls[r][c] = (__bf16)in[(size_t)(r0 + r) * C + c0 + c];
  }
  __syncthreads();
#pragma unroll
  for (int i = 0; i < 2; i++) {
    int idx = tid + i * 256;      // 0..511
    int cc = idx >> 3;            // output row (source col) 0..63
    int rr8 = (idx & 7) * 8;      // 8-wide output col group
    bf16x8 v;
#pragma unroll
    for (int j = 0; j < 8; j++) v[j] = tls[rr8 + j][cc];
    *(bf16x8*)&out[(size_t)(c0 + cc) * R + r0 + rr8] = v;
  }
}

// ======== GEMMs (r9-validated): 2-barrier BK=64 structure. r12/r13 falsified
// intra-block SW pipelining; r14 falsified kv re-tiling. ====================
#define BUFE 4096   // 128 rows x 32 cols (A tile per kh)
#define BUFEB 2048  // 64 rows x 32 cols (B tile per kh)

// ---------- gemm_a64: 128x64 tiles (640 blocks, 2.5/CU). ckv & q ------------
// q scale folds 1/8 (softmax scale) * log2(e) so attn can use exp2.
__global__ __launch_bounds__(256) void gemm_a64(const __bf16* __restrict__ A,
                                                const __bf16* __restrict__ B1,
                                                const __bf16* __restrict__ B2,
                                                __bf16* __restrict__ C1,
                                                __bf16* __restrict__ C2) {
  __shared__ __attribute__((aligned(16))) __bf16 Al[2][BUFE];
  __shared__ __attribute__((aligned(16))) __bf16 Bl[2][BUFEB];
  int tid = threadIdx.x;
  int w = tid >> 6, lane = tid & 63;
  int quad = lane >> 4, l16 = lane & 15;
  int mw = w & 1, nw = w >> 1;
  int bx = blockIdx.x, m0 = blockIdx.y * 128;
  const __bf16* Bt;
  __bf16* C;
  int n0, N;
  float sc;
  if (bx < 4) { Bt = B1; C = C1; n0 = bx * 64; N = DLAT; sc = 1.0f; }
  else        { Bt = B2; C = C2; n0 = (bx - 4) * 64; N = DIMX;
                sc = 0.125f * 1.44269504088896340736f; }
  const int K = DIMX;
  int arow = w * 32 + (lane >> 2), acol = (lane & 3) << 3;
  int brow = w * 16 + (lane >> 2);

  floatx4 acc[4][2];
#pragma unroll
  for (int i = 0; i < 4; i++)
#pragma unroll
    for (int j = 0; j < 2; j++) acc[i][j] = (floatx4){0.f, 0.f, 0.f, 0.f};

  for (int k0 = 0; k0 < K; k0 += 64) {
#pragma unroll
    for (int kh = 0; kh < 2; kh++) {
#pragma unroll
      for (int j = 0; j < 2; j++)
        gload_lds16(A + (size_t)(m0 + arow + j * 16) * K + k0 + kh * 32 + acol,
                    &Al[kh][(w * 32 + j * 16) * 32]);
      gload_lds16(Bt + (size_t)(n0 + brow) * K + k0 + kh * 32 + acol,
                  &Bl[kh][(w * 16) * 32]);
    }
    __syncthreads();
#pragma unroll
    for (int kh = 0; kh < 2; kh++) {
      bf16x8 af[4], bfr[2];
#pragma unroll
      for (int mt = 0; mt < 4; mt++)
        af[mt] =
            *(const bf16x8*)&Al[kh][(mw * 64 + mt * 16 + l16) * 32 + quad * 8];
#pragma unroll
      for (int nt = 0; nt < 2; nt++)
        bfr[nt] =
            *(const bf16x8*)&Bl[kh][(nw * 32 + nt * 16 + l16) * 32 + quad * 8];
#pragma unroll
      for (int mt = 0; mt < 4; mt++)
#pragma unroll
        for (int nt = 0; nt < 2; nt++)
          acc[mt][nt] = MFMA(af[mt], bfr[nt], acc[mt][nt]);
    }
    __syncthreads();
  }
#pragma unroll
  for (int mt = 0; mt < 4; mt++)
#pragma unroll
    for (int nt = 0; nt < 2; nt++)
#pragma unroll
      for (int r = 0; r < 4; r++) {
        int row = m0 + mw * 64 + mt * 16 + quad * 4 + r;
        int col = n0 + nw * 32 + nt * 16 + l16;
        C[(size_t)row * N + col] = (__bf16)(acc[mt][nt][r] * sc);
      }
}

// ---------- gemm_kv128: k = ckv@Wuk' (bx<8); vt = (ckv@Wuv')^T (bx>=8) ------
__global__ __launch_bounds__(256) void gemm_kv128(const __bf16* __restrict__ A,
                                                  const __bf16* __restrict__ Bk,
                                                  const __bf16* __restrict__ Bv,
                                                  __bf16* __restrict__ k,
                                                  __bf16* __restrict__ vt) {
  __shared__ __attribute__((aligned(16))) __bf16 Al[2][BUFE];
  __shared__ __attribute__((aligned(16))) __bf16 Bl[2][BUFE];
  __shared__ __attribute__((aligned(16))) __bf16 tw[4][64 * 72];
  int tid = threadIdx.x;
  int w = tid >> 6, lane = tid & 63;
  int quad = lane >> 4, l16 = lane & 15;
  int mw = w & 1, nw = w >> 1;
  int bx = blockIdx.x, m0 = blockIdx.y * 128;
  bool is_k = (bx < 8);
  const __bf16* Bt = is_k ? Bk : Bv;
  int n0 = (is_k ? bx : bx - 8) * 128;
  const int K = DLAT;
  int arow = w * 32 + (lane >> 2), acol = (lane & 3) << 3;

  floatx4 acc[4][4];
#pragma unroll
  for (int i = 0; i < 4; i++)
#pragma unroll
    for (int j = 0; j < 4; j++) acc[i][j] = (floatx4){0.f, 0.f, 0.f, 0.f};

  for (int k0 = 0; k0 < K; k0 += 64) {
#pragma unroll
    for (int kh = 0; kh < 2; kh++)
#pragma unroll
      for (int j = 0; j < 2; j++) {
        gload_lds16(A + (size_t)(m0 + arow + j * 16) * K + k0 + kh * 32 + acol,
                    &Al[kh][(w * 32 + j * 16) * 32]);
        gload_lds16(Bt + (size_t)(n0 + arow + j * 16) * K + k0 + kh * 32 + acol,
                    &Bl[kh][(w * 32 + j * 16) * 32]);
      }
    __syncthreads();
#pragma unroll
    for (int kh = 0; kh < 2; kh++) {
      bf16x8 af[4], bfr[4];
#pragma unroll
      for (int mt = 0; mt < 4; mt++)
        af[mt] =
            *(const bf16x8*)&Al[kh][(mw * 64 + mt * 16 + l16) * 32 + quad * 8];
#pragma unroll
      for (int nt = 0; nt < 4; nt++)
        bfr[nt] =
            *(const bf16x8*)&Bl[kh][(nw * 64 + nt * 16 + l16) * 32 + quad * 8];
#pragma unroll
      for (int mt = 0; mt < 4; mt++)
#pragma unroll
        for (int nt = 0; nt < 4; nt++)
          acc[mt][nt] = MFMA(af[mt], bfr[nt], acc[mt][nt]);
    }
    __syncthreads();
  }
  if (is_k) {
#pragma unroll
    for (int mt = 0; mt < 4; mt++)
#pragma unroll
      for (int nt = 0; nt < 4; nt++)
#pragma unroll
        for (int r = 0; r < 4; r++) {
          int row = m0 + mw * 64 + mt * 16 + quad * 4 + r;
          int col = n0 + nw * 64 + nt * 16 + l16;
          k[(size_t)row * DIMX + col] = (__bf16)acc[mt][nt][r];
        }
  } else {
#pragma unroll
    for (int mt = 0; mt < 4; mt++)
#pragma unroll
      for (int nt = 0; nt < 4; nt++)
#pragma unroll
        for (int r = 0; r < 4; r++)
          tw[w][(nt * 16 + l16) * 72 + mt * 16 + quad * 4 + r] =
              (__bf16)acc[mt][nt][r];
    int cbase = lane >> 3, chunk = lane & 7;
#pragma unroll
    for (int i = 0; i < 8; i++) {
      int c = cbase + i * 8;
      bf16x8 v8 = *(const bf16x8*)&tw[w][c * 72 + chunk * 8];
      *(bf16x8*)&vt[(size_t)(n0 + nw * 64 + c) * T_SEQ + m0 + mw * 64 +
                    chunk * 8] = v8;
    }
  }
}

// ---------- gemm_f64: out(f32) = ctx @ Wo', 128x64 tiles (512 blocks) ------
__global__ __launch_bounds__(256) void gemm_f64(const __bf16* __restrict__ A,
                                                const __bf16* __restrict__ Bt,
                                                float* __restrict__ C) {
  __shared__ __attribute__((aligned(16))) __bf16 Al[2][BUFE];
  __shared__ __attribute__((aligned(16))) __bf16 Bl[2][BUFEB];
  int tid = threadIdx.x;
  int w = tid >> 6, lane = tid & 63;
  int quad = lane >> 4, l16 = lane & 15;
  int mw = w & 1, nw = w >> 1;
  int n0 = blockIdx.x * 64, m0 = blockIdx.y * 128;
  const int K = DIMX, N = DIMX;
  int arow = w * 32 + (lane >> 2), acol = (lane & 3) << 3;
  int brow = w * 16 + (lane >> 2);

  floatx4 acc[4][2];
#pragma unroll
  for (int i = 0; i < 4; i++)
#pragma unroll
    for (int j = 0; j < 2; j++) acc[i][j] = (floatx4){0.f, 0.f, 0.f, 0.f};

  for (int k0 = 0; k0 < K; k0 += 64) {
#pragma unroll
    for (int kh = 0; kh < 2; kh++) {
#pragma unroll
      for (int j = 0; j < 2; j++)
        gload_lds16(A + (size_t)(m0 + arow + j * 16) * K + k0 + kh * 32 + acol,
                    &Al[kh][(w * 32 + j * 16) * 32]);
      gload_lds16(Bt + (size_t)(n0 + brow) * K + k0 + kh * 32 + acol,
                  &Bl[kh][(w * 16) * 32]);
    }
    __syncthreads();
#pragma unroll
    for (int kh = 0; kh < 2; kh++) {
      bf16x8 af[4], bfr[2];
#pragma unroll
      for (int mt = 0; mt < 4; mt++)
        af[mt] =
            *(const bf16x8*)&Al[kh][(mw * 64 + mt * 16 + l16) * 32 + quad * 8];
#pragma unroll
      for (int nt = 0; nt < 2; nt++)
        bfr[nt] =
            *(const bf16x8*)&Bl[kh][(nw * 32 + nt * 16 + l16) * 32 + quad * 8];
#pragma unroll
      for (int mt = 0; mt < 4; mt++)
#pragma unroll
        for (int nt = 0; nt < 2; nt++)
          acc[mt][nt] = MFMA(af[mt], bfr[nt], acc[mt][nt]);
    }
    __syncthreads();
  }
#pragma unroll
  for (int mt = 0; mt < 4; mt++)
#pragma unroll
    for (int nt = 0; nt < 2; nt++)
#pragma unroll
      for (int r = 0; r < 4; r++) {
        int row = m0 + mw * 64 + mt * 16 + quad * 4 + r;
        int col = n0 + nw * 32 + nt * 16 + l16;
        C[(size_t)row * N + col] = acc[mt][nt][r];
      }
}

// ---------- flash attention v12 (r11-validated: 67.5us steady-state) --------
// DMA staging with pre-swizzled global source, linear LDS dest (rule #21);
// swapped-QK in-lane P, exp2 via pre-scaled q, global-LPT 1024-block grid.
#define PST 72
__global__ __launch_bounds__(256, 3) void mla_attn12(
    const __bf16* __restrict__ Q, const __bf16* __restrict__ Kg,
    const __bf16* __restrict__ Vt, __bf16* __restrict__ ctx) {
  __shared__ __attribute__((aligned(16))) __bf16 Kl[2][64 * 64];
  __shared__ __attribute__((aligned(16))) __bf16 Vl[2][64 * 64];
  __shared__ __attribute__((aligned(16))) __bf16 Pl[64 * PST];
  int tid = threadIdx.x;
  int wave = tid >> 6, lane = tid & 63;
  int quad = lane >> 4, l16 = lane & 15;
  int h = blockIdx.x;        // heads vary fastest in dispatch order
  int qt = 63 - blockIdx.y;  // global LPT: all large blocks dispatch first
  int q0 = qt * 64;
  int srow = tid >> 3, pos = tid & 7;  // srow 0..31, rows srow and srow+32
  int gco = pos << 3;
  int sw = (pos ^ (srow & 7)) << 3;    // pre-swizzled source column (elements)
  int fr = (wave * 16 + l16) * PST;
  int c0s = ((quad ^ (l16 & 7)) << 3);
  int c1s = (((4 + quad) ^ (l16 & 7)) << 3);
  int wb = wave * 512;  // wave-uniform LDS base (elements)

  *(bf16x8*)&Pl[srow * PST + gco] =
      *(const bf16x8*)&Q[(size_t)(q0 + srow) * DIMX + h * HD + gco];
  *(bf16x8*)&Pl[(srow + 32) * PST + gco] =
      *(const bf16x8*)&Q[(size_t)(q0 + srow + 32) * DIMX + h * HD + gco];
  gload_lds16(&Kg[(size_t)srow * DIMX + h * HD + sw], &Kl[0][wb]);
  gload_lds16(&Kg[(size_t)(srow + 32) * DIMX + h * HD + sw], &Kl[0][2048 + wb]);
  gload_lds16(&Vt[(size_t)(h * HD + srow) * T_SEQ + sw], &Vl[0][wb]);
  gload_lds16(&Vt[(size_t)(h * HD + srow + 32) * T_SEQ + sw], &Vl[0][2048 + wb]);
  __syncthreads();
  bf16x8 qf0 = *(const bf16x8*)&Pl[fr + quad * 8];
  bf16x8 qf1 = *(const bf16x8*)&Pl[fr + 32 + quad * 8];

  floatx4 o[4];
  float lsum = 0.f;
#pragma unroll
  for (int i = 0; i < 4; i++) o[i] = (floatx4){0.f, 0.f, 0.f, 0.f};

  for (int kt = 0; kt <= qt; kt++) {
    int cur = kt & 1, nxt = cur ^ 1;
    bool pre = (kt < qt);
    if (pre) {  // DMA next tile into nxt (quiesced by the previous barrier)
      int k0n = (kt + 1) * 64;
      gload_lds16(&Kg[(size_t)(k0n + srow) * DIMX + h * HD + sw],
                  &Kl[nxt][wb]);
      gload_lds16(&Kg[(size_t)(k0n + srow + 32) * DIMX + h * HD + sw],
                  &Kl[nxt][2048 + wb]);
      gload_lds16(&Vt[(size_t)(h * HD + srow) * T_SEQ + k0n + sw],
                  &Vl[nxt][wb]);
      gload_lds16(&Vt[(size_t)(h * HD + srow + 32) * T_SEQ + k0n + sw],
                  &Vl[nxt][2048 + wb]);
    }
    const __bf16* Kc = Kl[cur];
    const __bf16* Vc = Vl[cur];
    floatx4 s[4];
    __builtin_amdgcn_s_setprio(1);
#pragma unroll
    for (int ct = 0; ct < 4; ct++) {
      int rb = (ct * 16 + l16) * 64;
      bf16x8 kf0 = *(const bf16x8*)&Kc[rb + c0s];
      bf16x8 kf1 = *(const bf16x8*)&Kc[rb + c1s];
      floatx4 z = (floatx4){0.f, 0.f, 0.f, 0.f};
      z = MFMA(kf0, qf0, z);  // swapped: lane holds P[q=l16][k=ct*16+quad*4+r]
      z = MFMA(kf1, qf1, z);
      s[ct] = z;
    }
    __builtin_amdgcn_s_setprio(0);
    bool diag = (kt == qt);
#pragma unroll
    for (int ct = 0; ct < 4; ct++) {
      float p0[4];
#pragma unroll
      for (int r = 0; r < 4; r++) {
        float p = __builtin_amdgcn_exp2f(s[ct][r]);
        if (diag && (ct * 16 + quad * 4 + r > wave * 16 + l16)) p = 0.f;
        lsum += p;
        p0[r] = p;
      }
      bf16x4 pk = {(__bf16)p0[0], (__bf16)p0[1], (__bf16)p0[2], (__bf16)p0[3]};
      *(bf16x4*)&Pl[(wave * 16 + l16) * PST + ct * 16 + quad * 4] = pk;
    }
    bf16x8 pf0 = *(const bf16x8*)&Pl[fr + quad * 8];
    bf16x8 pf1 = *(const bf16x8*)&Pl[fr + 32 + quad * 8];
    __builtin_amdgcn_s_setprio(1);
#pragma unroll
    for (int dt = 0; dt < 4; dt++) {
      int rb = (dt * 16 + l16) * 64;
      bf16x8 vf0 = *(const bf16x8*)&Vc[rb + c0s];
      bf16x8 vf1 = *(const bf16x8*)&Vc[rb + c1s];
      o[dt] = MFMA(pf0, vf0, o[dt]);
      o[dt] = MFMA(pf1, vf1, o[dt]);
    }
    __builtin_amdgcn_s_setprio(0);
    __syncthreads();
  }

  lsum += __shfl_xor(lsum, 16, 64);
  lsum += __shfl_xor(lsum, 32, 64);
  float inv[4];
#pragma unroll
  for (int r = 0; r < 4; r++) inv[r] = 1.0f / __shfl(lsum, quad * 4 + r, 16);

#pragma unroll
  for (int dt = 0; dt < 4; dt++)
#pragma unroll
    for (int r = 0; r < 4; r++) {
      float val = o[dt][r] * inv[r];
      int row = q0 + wave * 16 + quad * 4 + r;
      int col = h * HD + dt * 16 + l16;
      ctx[(size_t)row * DIMX + col] = (__bf16)val;
    }
}

extern "C" void kernel_launch(void* const* d_in, const int* in_sizes, int n_in,
                              void* d_out, int out_size, void* d_ws,
                              size_t ws_size, hipStream_t stream) {
  const float* x = (const float*)d_in[0];
  const float* wdkv = (const float*)d_in[1];
  const float* wuk = (const float*)d_in[2];
  const float* wuv = (const float*)d_in[3];
  const float* wuq = (const float*)d_in[4];
  const float* wo = (const float*)d_in[5];
  float* out = (float*)d_out;

  __bf16* ws = (__bf16*)d_ws;
  __bf16* x_bf = ws;                               // T*D
  __bf16* q = x_bf + (size_t)T_SEQ * DIMX;         // T*D (pre-scaled)
  __bf16* k = q + (size_t)T_SEQ * DIMX;            // T*D
  __bf16* vt = k + (size_t)T_SEQ * DIMX;           // D*T
  __bf16* ctx = vt + (size_t)T_SEQ * DIMX;         // T*D
  __bf16* ckv = ctx + (size_t)T_SEQ * DIMX;        // T*DLAT
  __bf16* wt_dkv = ckv + (size_t)T_SEQ * DLAT;     // DLAT x DIM
  __bf16* wt_uk = wt_dkv + (size_t)DLAT * DIMX;    // DIM x DLAT
  __bf16* wt_uv = wt_uk + (size_t)DIMX * DLAT;     // DIM x DLAT
  __bf16* wt_uq = wt_uv + (size_t)DIMX * DLAT;     // DIM x DIM
  __bf16* wt_o = wt_uq + (size_t)DIMX * DIMX;      // DIM x DIM

  dim3 blk(256);
  prep_kernel<<<dim3(2752), blk, 0, stream>>>(x, wdkv, wuk, wuv, wuq, wo, x_bf,
                                              wt_dkv, wt_uk, wt_uv, wt_uq, wt_o);
  gemm_a64<<<dim3(20, T_SEQ / 128), blk, 0, stream>>>(x_bf, wt_dkv, wt_uq,
                                                      ckv, q);
  gemm_kv128<<<dim3(16, T_SEQ / 128), blk, 0, stream>>>(ckv, wt_uk, wt_uv, k,
                                                        vt);
  mla_attn12<<<dim3(NH, 64), dim3(256), 0, stream>>>(q, k, vt, ctx);
  gemm_f64<<<dim3(DIMX / 64, T_SEQ / 128), blk, 0, stream>>>(ctx, wt_o, out);
}